// Round 3
// baseline (624.823 us; speedup 1.0000x reference)
//
#include <hip/hip_runtime.h>
#include <cstdint>
#include <cstddef>

// ---------------------------------------------------------------------------
// 3-layer GCN forward (PyG GCNConv semantics) + global_add_pool.
// Strategy: build dst-grouped CSR once per launch (counting atomics + scan +
// placement atomics), then each layer is GEMM (fp32, W in LDS) followed by
// atomic-free per-node aggregation (one wave per node, coalesced row gathers).
// Layer 3 aggregation fuses the graph pooling via fp32 atomics into d_out.
// ---------------------------------------------------------------------------

static inline int cdiv_i(int a, int b) { return (a + b - 1) / b; }

__global__ void zero_f32_kernel(float* __restrict__ p, int n) {
    int i = blockIdx.x * 256 + threadIdx.x;
    if (i < n) p[i] = 0.0f;
}

__global__ void zero_i32_kernel(int* __restrict__ p, int n) {
    int i = blockIdx.x * 256 + threadIdx.x;
    if (i < n) p[i] = 0;
}

// count in-degree (real edges only; self-loop added analytically later)
__global__ void count_kernel(const int* __restrict__ dst, int* __restrict__ cnt, int E) {
    int i = blockIdx.x * 256 + threadIdx.x;
    if (i < E) atomicAdd(&cnt[dst[i]], 1);
}

// dinv[i] = rsqrt(indeg + 1)   (deg always >0 due to self-loop)
__global__ void dinv_kernel(const int* __restrict__ cnt, float* __restrict__ dinv, int n) {
    int i = blockIdx.x * 256 + threadIdx.x;
    if (i < n) dinv[i] = rsqrtf((float)(cnt[i] + 1));
}

// single-block exclusive scan of cnt -> off[0..n], tiles of 1024 (256 thr x 4)
__global__ __launch_bounds__(256) void scan_kernel(const int* __restrict__ cnt,
                                                   int* __restrict__ off, int n) {
    __shared__ int wsum[4];
    __shared__ int carry_s;
    int tid = threadIdx.x;
    int lane = tid & 63, wid = tid >> 6;
    if (tid == 0) carry_s = 0;
    __syncthreads();
    int ntiles = (n + 1023) / 1024;
    for (int t = 0; t < ntiles; ++t) {
        int i0 = t * 1024 + tid * 4;
        int v0 = (i0 + 0 < n) ? cnt[i0 + 0] : 0;
        int v1 = (i0 + 1 < n) ? cnt[i0 + 1] : 0;
        int v2 = (i0 + 2 < n) ? cnt[i0 + 2] : 0;
        int v3 = (i0 + 3 < n) ? cnt[i0 + 3] : 0;
        int local = v0 + v1 + v2 + v3;
        int s = local;
        #pragma unroll
        for (int d = 1; d < 64; d <<= 1) {
            int u = __shfl_up(s, d, 64);
            if (lane >= d) s += u;
        }
        if (lane == 63) wsum[wid] = s;
        __syncthreads();
        int woff = 0;
        for (int w = 0; w < wid; ++w) woff += wsum[w];
        int carry = carry_s;
        int excl = carry + woff + (s - local);
        if (i0 + 0 < n) off[i0 + 0] = excl;
        if (i0 + 1 < n) off[i0 + 1] = excl + v0;
        if (i0 + 2 < n) off[i0 + 2] = excl + v0 + v1;
        if (i0 + 3 < n) off[i0 + 3] = excl + v0 + v1 + v2;
        __syncthreads();
        if (tid == 255) carry_s = carry + woff + s;
        __syncthreads();
    }
    if (tid == 0) off[n] = carry_s;
}

__global__ void copy_i32_kernel(const int* __restrict__ a, int* __restrict__ b, int n) {
    int i = blockIdx.x * 256 + threadIdx.x;
    if (i < n) b[i] = a[i];
}

// scatter edges into dst-grouped CSR slots; precompute norm = dinv[s]*dinv[d]
__global__ void fill_kernel(const int* __restrict__ src, const int* __restrict__ dst,
                            const float* __restrict__ dinv, int* __restrict__ cursor,
                            int* __restrict__ csr_src, float* __restrict__ csr_norm, int E) {
    int i = blockIdx.x * 256 + threadIdx.x;
    if (i < E) {
        int s = src[i], d = dst[i];
        int pos = atomicAdd(&cursor[d], 1);
        csr_src[pos] = s;
        csr_norm[pos] = dinv[s] * dinv[d];
    }
}

// out[n,128] = A[n,128] @ W[128,128]; W staged fully in LDS (64 KB).
// Block: 256 thr = 4 waves; wave covers 2 rows (half-wave each), 4 cols/lane.
__global__ __launch_bounds__(256) void gemm_kernel(const float* __restrict__ A,
                                                   const float* __restrict__ W,
                                                   float* __restrict__ out, int n) {
    __shared__ __align__(16) float Wl[128 * 128];
    __shared__ __align__(16) float Al[8 * 128];
    for (int i = threadIdx.x; i < 4096; i += 256)
        ((float4*)Wl)[i] = ((const float4*)W)[i];
    int wave = threadIdx.x >> 6;
    int lane = threadIdx.x & 63;
    int half = lane >> 5;
    int cg = lane & 31;
    int r = wave * 2 + half;  // 0..7 row within tile
    for (int rbase = blockIdx.x * 8; rbase < n; rbase += gridDim.x * 8) {
        __syncthreads();  // also covers initial W staging
        int rows = min(8, n - rbase);
        for (int i = threadIdx.x; i < rows * 32; i += 256) {
            int rr = i >> 5, cc = i & 31;
            ((float4*)(Al + rr * 128))[cc] =
                ((const float4*)(A + (size_t)(rbase + rr) * 128))[cc];
        }
        __syncthreads();
        if (rbase + r < n) {
            float4 acc = make_float4(0.f, 0.f, 0.f, 0.f);
            #pragma unroll 16
            for (int k = 0; k < 128; ++k) {
                float a = Al[r * 128 + k];
                float4 w = ((const float4*)(Wl + k * 128))[cg];
                acc.x = fmaf(a, w.x, acc.x);
                acc.y = fmaf(a, w.y, acc.y);
                acc.z = fmaf(a, w.z, acc.z);
                acc.w = fmaf(a, w.w, acc.w);
            }
            ((float4*)(out + (size_t)(rbase + r) * 128))[cg] = acc;
        }
    }
}

// One wave per node: out[i] = b + dinv[i]^2*h[i] + sum_e norm_e * h[src_e].
// Wave-uniform edge loop -> scalar loads of csr_src/csr_norm; 512B row gathers.
template <int RELU, int POOL>
__global__ __launch_bounds__(256) void agg_kernel(
    const float* __restrict__ h, const int* __restrict__ off,
    const int* __restrict__ csr_src, const float* __restrict__ csr_norm,
    const float* __restrict__ dinv, const float* __restrict__ bias,
    const int* __restrict__ batch, float* __restrict__ out, int n) {
    int node = blockIdx.x * 4 + (threadIdx.x >> 6);
    if (node >= n) return;
    int lane = threadIdx.x & 63;
    int c2 = lane * 2;
    float di = dinv[node];
    float2 hv = *(const float2*)(h + (size_t)node * 128 + c2);
    float a0 = fmaf(di * di, hv.x, bias[c2]);
    float a1 = fmaf(di * di, hv.y, bias[c2 + 1]);
    int e0 = off[node], e1 = off[node + 1];
    for (int e = e0; e < e1; ++e) {
        int s = csr_src[e];
        float w = csr_norm[e];
        float2 v = *(const float2*)(h + (size_t)s * 128 + c2);
        a0 = fmaf(w, v.x, a0);
        a1 = fmaf(w, v.y, a1);
    }
    if (RELU) { a0 = fmaxf(a0, 0.f); a1 = fmaxf(a1, 0.f); }
    if (POOL) {
        int g = batch[node];
        atomicAdd(out + (size_t)g * 128 + c2, a0);
        atomicAdd(out + (size_t)g * 128 + c2 + 1, a1);
    } else {
        *(float2*)(out + (size_t)node * 128 + c2) = make_float2(a0, a1);
    }
}

extern "C" void kernel_launch(void* const* d_in, const int* in_sizes, int n_in,
                              void* d_out, int out_size, void* d_ws, size_t ws_size,
                              hipStream_t stream) {
    const float* x   = (const float*)d_in[0];
    const int*   ei  = (const int*)d_in[1];
    const int*   bat = (const int*)d_in[2];
    const float* W1  = (const float*)d_in[3];
    const float* b1  = (const float*)d_in[4];
    const float* W2  = (const float*)d_in[5];
    const float* b2  = (const float*)d_in[6];
    const float* W3  = (const float*)d_in[7];
    const float* b3  = (const float*)d_in[8];
    float* outp = (float*)d_out;

    const int N = in_sizes[0] / 128;   // 50000
    const int E = in_sizes[1] / 2;     // 800000
    const int* src = ei;
    const int* dst = ei + E;

    // workspace carve-up (256B aligned)
    char* p = (char*)d_ws;
    auto alloc = [&](size_t bytes) -> void* {
        void* r = (void*)p;
        p += (bytes + 255) & ~(size_t)255;
        return r;
    };
    int*   cnt      = (int*)alloc((size_t)N * 4);
    int*   off      = (int*)alloc((size_t)(N + 1) * 4);
    int*   cursor   = (int*)alloc((size_t)N * 4);
    float* dinv     = (float*)alloc((size_t)N * 4);
    int*   csr_src  = (int*)alloc((size_t)E * 4);
    float* csr_norm = (float*)alloc((size_t)E * 4);
    float* bufA     = (float*)alloc((size_t)N * 128 * 4);
    float* bufB     = (float*)alloc((size_t)N * 128 * 4);

    // ---- setup: degrees, dinv, CSR ----
    hipLaunchKernelGGL(zero_f32_kernel, dim3(cdiv_i(out_size, 256)), dim3(256), 0, stream,
                       outp, out_size);
    hipLaunchKernelGGL(zero_i32_kernel, dim3(cdiv_i(N, 256)), dim3(256), 0, stream, cnt, N);
    hipLaunchKernelGGL(count_kernel, dim3(cdiv_i(E, 256)), dim3(256), 0, stream, dst, cnt, E);
    hipLaunchKernelGGL(dinv_kernel, dim3(cdiv_i(N, 256)), dim3(256), 0, stream, cnt, dinv, N);
    hipLaunchKernelGGL(scan_kernel, dim3(1), dim3(256), 0, stream, cnt, off, N);
    hipLaunchKernelGGL(copy_i32_kernel, dim3(cdiv_i(N, 256)), dim3(256), 0, stream, off, cursor, N);
    hipLaunchKernelGGL(fill_kernel, dim3(cdiv_i(E, 256)), dim3(256), 0, stream,
                       src, dst, dinv, cursor, csr_src, csr_norm, E);

    const int gemm_grid = 1024;
    const int agg_grid  = cdiv_i(N, 4);

    // ---- layer 1 ----
    hipLaunchKernelGGL(gemm_kernel, dim3(gemm_grid), dim3(256), 0, stream, x, W1, bufA, N);
    hipLaunchKernelGGL((agg_kernel<1, 0>), dim3(agg_grid), dim3(256), 0, stream,
                       bufA, off, csr_src, csr_norm, dinv, b1, bat, bufB, N);
    // ---- layer 2 ----
    hipLaunchKernelGGL(gemm_kernel, dim3(gemm_grid), dim3(256), 0, stream, bufB, W2, bufA, N);
    hipLaunchKernelGGL((agg_kernel<1, 0>), dim3(agg_grid), dim3(256), 0, stream,
                       bufA, off, csr_src, csr_norm, dinv, b2, bat, bufB, N);
    // ---- layer 3 + fused pooling ----
    hipLaunchKernelGGL(gemm_kernel, dim3(gemm_grid), dim3(256), 0, stream, bufB, W3, bufA, N);
    hipLaunchKernelGGL((agg_kernel<0, 1>), dim3(agg_grid), dim3(256), 0, stream,
                       bufA, off, csr_src, csr_norm, dinv, b3, bat, outp, N);
}

// Round 6
// 552.686 us; speedup vs baseline: 1.1305x; 1.1305x over previous
//
#include <hip/hip_runtime.h>
#include <cstdint>
#include <cstddef>

// ---------------------------------------------------------------------------
// 3-layer GCN + global_add_pool.
// R4 changes vs R3 (dur 625us, agg=3x100us FETCH=187MB, gemm~3x90us VALU-bound):
//  - h (gather operand) stored bf16: halves the L2-miss gather traffic.
//  - GEMM on matrix cores: fp32 emulated as hi/lo bf16 split (3 MFMAs per
//    product, ~2^-15 rel err). W pre-split into fragment-ordered arrays so
//    the B-fragment is one 16B per-lane global load (L2-resident, no LDS).
//  - agg epilogue emits hi/lo bf16 pair (next GEMM's A operand) for free.
// ---------------------------------------------------------------------------

typedef __attribute__((ext_vector_type(8))) short short8b;  // 8 bf16 = 4 VGPR
typedef __attribute__((ext_vector_type(4))) float f32x4;

static inline int cdiv_i(int a, int b) { return (a + b - 1) / b; }

__device__ inline unsigned short f2bf(float f) {  // RNE f32->bf16
    union { float f; unsigned int u; } v; v.f = f;
    unsigned int r = v.u + 0x7fffu + ((v.u >> 16) & 1u);
    return (unsigned short)(r >> 16);
}
__device__ inline float bf2f(unsigned short b) {
    union { unsigned int u; float f; } v; v.u = ((unsigned int)b) << 16;
    return v.f;
}
__device__ inline float bflo(unsigned int u) {  // low bf16 of packed pair
    union { unsigned int x; float f; } v; v.x = u << 16; return v.f;
}
__device__ inline float bfhi(unsigned int u) {  // high bf16 of packed pair
    union { unsigned int x; float f; } v; v.x = u & 0xffff0000u; return v.f;
}

__global__ void zero_f32_kernel(float* __restrict__ p, int n) {
    int i = blockIdx.x * 256 + threadIdx.x;
    if (i < n) p[i] = 0.0f;
}
__global__ void zero_i32_kernel(int* __restrict__ p, int n) {
    int i = blockIdx.x * 256 + threadIdx.x;
    if (i < n) p[i] = 0;
}
__global__ void count_kernel(const int* __restrict__ dst, int* __restrict__ cnt, int E) {
    int i = blockIdx.x * 256 + threadIdx.x;
    if (i < E) atomicAdd(&cnt[dst[i]], 1);
}
__global__ void dinv_kernel(const int* __restrict__ cnt, float* __restrict__ dinv, int n) {
    int i = blockIdx.x * 256 + threadIdx.x;
    if (i < n) dinv[i] = rsqrtf((float)(cnt[i] + 1));
}

// single-block exclusive scan (unchanged from R3 — not in top-5)
__global__ __launch_bounds__(256) void scan_kernel(const int* __restrict__ cnt,
                                                   int* __restrict__ off, int n) {
    __shared__ int wsum[4];
    __shared__ int carry_s;
    int tid = threadIdx.x;
    int lane = tid & 63, wid = tid >> 6;
    if (tid == 0) carry_s = 0;
    __syncthreads();
    int ntiles = (n + 1023) / 1024;
    for (int t = 0; t < ntiles; ++t) {
        int i0 = t * 1024 + tid * 4;
        int v0 = (i0 + 0 < n) ? cnt[i0 + 0] : 0;
        int v1 = (i0 + 1 < n) ? cnt[i0 + 1] : 0;
        int v2 = (i0 + 2 < n) ? cnt[i0 + 2] : 0;
        int v3 = (i0 + 3 < n) ? cnt[i0 + 3] : 0;
        int local = v0 + v1 + v2 + v3;
        int s = local;
        #pragma unroll
        for (int d = 1; d < 64; d <<= 1) {
            int u = __shfl_up(s, d, 64);
            if (lane >= d) s += u;
        }
        if (lane == 63) wsum[wid] = s;
        __syncthreads();
        int woff = 0;
        for (int w = 0; w < wid; ++w) woff += wsum[w];
        int carry = carry_s;
        int excl = carry + woff + (s - local);
        if (i0 + 0 < n) off[i0 + 0] = excl;
        if (i0 + 1 < n) off[i0 + 1] = excl + v0;
        if (i0 + 2 < n) off[i0 + 2] = excl + v0 + v1;
        if (i0 + 3 < n) off[i0 + 3] = excl + v0 + v1 + v2;
        __syncthreads();
        if (tid == 255) carry_s = carry + woff + s;
        __syncthreads();
    }
    if (tid == 0) off[n] = carry_s;
}

__global__ void copy_i32_kernel(const int* __restrict__ a, int* __restrict__ b, int n) {
    int i = blockIdx.x * 256 + threadIdx.x;
    if (i < n) b[i] = a[i];
}

__global__ void fill_kernel(const int* __restrict__ src, const int* __restrict__ dst,
                            const float* __restrict__ dinv, int* __restrict__ cursor,
                            int* __restrict__ csr_src, float* __restrict__ csr_norm, int E) {
    int i = blockIdx.x * 256 + threadIdx.x;
    if (i < E) {
        int s = src[i], d = dst[i];
        int pos = atomicAdd(&cursor[d], 1);
        csr_src[pos] = s;
        csr_norm[pos] = dinv[s] * dinv[d];
    }
}

// x fp32 -> xhi/xlo bf16 (4 elems/thread)
__global__ void split_x_kernel(const float* __restrict__ x,
                               unsigned short* __restrict__ xh,
                               unsigned short* __restrict__ xl, int n4) {
    int i = blockIdx.x * 256 + threadIdx.x;
    if (i >= n4) return;
    float4 v = ((const float4*)x)[i];
    unsigned short h0 = f2bf(v.x), h1 = f2bf(v.y), h2 = f2bf(v.z), h3 = f2bf(v.w);
    unsigned short l0 = f2bf(v.x - bf2f(h0)), l1 = f2bf(v.y - bf2f(h1));
    unsigned short l2 = f2bf(v.z - bf2f(h2)), l3 = f2bf(v.w - bf2f(h3));
    ushort4 hv; hv.x = h0; hv.y = h1; hv.z = h2; hv.w = h3;
    ushort4 lv; lv.x = l0; lv.y = l1; lv.z = l2; lv.w = l3;
    ((ushort4*)xh)[i] = hv;
    ((ushort4*)xl)[i] = lv;
}

// W[128][128] fp32 (row k, col n) -> hi/lo bf16 in MFMA B-fragment order:
// idx = ((kt*8+ct)*64 + lane)*8 + j  <->  k = kt*32+(lane>>4)*8+j, n = ct*16+(lane&15)
__global__ void split_w_kernel(const float* __restrict__ W,
                               unsigned short* __restrict__ Wh,
                               unsigned short* __restrict__ Wl) {
    int t = blockIdx.x * 256 + threadIdx.x;  // 0..16383
    if (t >= 16384) return;
    int j = t & 7, lane = (t >> 3) & 63, ct = (t >> 9) & 7, kt = (t >> 12) & 3;
    int k = kt * 32 + (lane >> 4) * 8 + j;
    int nn = ct * 16 + (lane & 15);
    float w = W[k * 128 + nn];
    unsigned short h = f2bf(w);
    Wh[t] = h;
    Wl[t] = f2bf(w - bf2f(h));
}

// C[n,128] = (Ahi+Alo)[n,128] @ (Whi+Wlo)[128,128] via 3 bf16 MFMA products.
// Block 256 thr = 4 waves; wave owns 32 rows (2 x 16-row stripes) x 128 cols.
// B-fragments read directly from fragment-ordered global arrays (L2-resident).
__global__ __launch_bounds__(256) void gemm_mfma_kernel(
    const unsigned short* __restrict__ Ahi, const unsigned short* __restrict__ Alo,
    const unsigned short* __restrict__ Whf, const unsigned short* __restrict__ Wlf,
    unsigned short* __restrict__ hout, int n) {
    int wave = threadIdx.x >> 6, lane = threadIdx.x & 63;
    int r0 = blockIdx.x * 128 + wave * 32;
    int arow0 = r0 + (lane & 15);
    int arow1 = arow0 + 16;
    int la0 = min(arow0, n - 1);
    int la1 = min(arow1, n - 1);
    int kgrp = (lane >> 4) * 8;

    f32x4 acc[2][8];
    #pragma unroll
    for (int s = 0; s < 2; ++s)
        #pragma unroll
        for (int c = 0; c < 8; ++c) acc[s][c] = (f32x4){0.f, 0.f, 0.f, 0.f};

    #pragma unroll
    for (int kt = 0; kt < 4; ++kt) {
        int koff = kt * 32 + kgrp;
        short8b a0h = *(const short8b*)(Ahi + (size_t)la0 * 128 + koff);
        short8b a0l = *(const short8b*)(Alo + (size_t)la0 * 128 + koff);
        short8b a1h = *(const short8b*)(Ahi + (size_t)la1 * 128 + koff);
        short8b a1l = *(const short8b*)(Alo + (size_t)la1 * 128 + koff);
        const unsigned short* wb = Whf + ((size_t)(kt * 8) * 64 + lane) * 8;
        const unsigned short* lb = Wlf + ((size_t)(kt * 8) * 64 + lane) * 8;
        #pragma unroll
        for (int ct = 0; ct < 8; ++ct) {
            short8b wh = *(const short8b*)(wb + (size_t)ct * 512);
            short8b wl = *(const short8b*)(lb + (size_t)ct * 512);
            acc[0][ct] = __builtin_amdgcn_mfma_f32_16x16x32_bf16(a0h, wh, acc[0][ct], 0, 0, 0);
            acc[1][ct] = __builtin_amdgcn_mfma_f32_16x16x32_bf16(a1h, wh, acc[1][ct], 0, 0, 0);
            acc[0][ct] = __builtin_amdgcn_mfma_f32_16x16x32_bf16(a0l, wh, acc[0][ct], 0, 0, 0);
            acc[1][ct] = __builtin_amdgcn_mfma_f32_16x16x32_bf16(a1l, wh, acc[1][ct], 0, 0, 0);
            acc[0][ct] = __builtin_amdgcn_mfma_f32_16x16x32_bf16(a0h, wl, acc[0][ct], 0, 0, 0);
            acc[1][ct] = __builtin_amdgcn_mfma_f32_16x16x32_bf16(a1h, wl, acc[1][ct], 0, 0, 0);
        }
    }
    // D layout: row = (lane>>4)*4 + reg, col = lane&15  [verified m89/m91]
    int rb = r0 + (lane >> 4) * 4;
    int col = lane & 15;
    #pragma unroll
    for (int s = 0; s < 2; ++s)
        #pragma unroll
        for (int ct = 0; ct < 8; ++ct)
            #pragma unroll
            for (int i = 0; i < 4; ++i) {
                int rr = rb + s * 16 + i;
                if (rr < n) hout[(size_t)rr * 128 + ct * 16 + col] = f2bf(acc[s][ct][i]);
            }
}

// One wave per node; h is bf16 (lane covers cols 2l,2l+1 via one 4B load).
// POOL=0: write hi/lo bf16 (next GEMM's A). POOL=1: fp32 atomics into d_out.
template <int RELU, int POOL>
__global__ __launch_bounds__(256) void agg_kernel(
    const unsigned short* __restrict__ h, const int* __restrict__ off,
    const int* __restrict__ csr_src, const float* __restrict__ csr_norm,
    const float* __restrict__ dinv, const float* __restrict__ bias,
    const int* __restrict__ batch,
    unsigned short* __restrict__ ah, unsigned short* __restrict__ al,
    float* __restrict__ pool_out, int n) {
    int node = blockIdx.x * 4 + (threadIdx.x >> 6);
    if (node >= n) return;
    int lane = threadIdx.x & 63;
    int c2 = lane * 2;
    float di = dinv[node];
    unsigned int hv = *(const unsigned int*)(h + (size_t)node * 128 + c2);
    float a0 = fmaf(di * di, bflo(hv), bias[c2]);
    float a1 = fmaf(di * di, bfhi(hv), bias[c2 + 1]);
    int e0 = off[node], e1 = off[node + 1];
    for (int e = e0; e < e1; ++e) {
        int s = csr_src[e];
        float w = csr_norm[e];
        unsigned int v = *(const unsigned int*)(h + (size_t)s * 128 + c2);
        a0 = fmaf(w, bflo(v), a0);
        a1 = fmaf(w, bfhi(v), a1);
    }
    if (RELU) { a0 = fmaxf(a0, 0.f); a1 = fmaxf(a1, 0.f); }
    if (POOL) {
        int g = batch[node];
        atomicAdd(pool_out + (size_t)g * 128 + c2, a0);
        atomicAdd(pool_out + (size_t)g * 128 + c2 + 1, a1);
    } else {
        unsigned short h0 = f2bf(a0), h1 = f2bf(a1);
        unsigned short l0 = f2bf(a0 - bf2f(h0)), l1 = f2bf(a1 - bf2f(h1));
        *(unsigned int*)(ah + (size_t)node * 128 + c2) =
            ((unsigned int)h1 << 16) | h0;
        *(unsigned int*)(al + (size_t)node * 128 + c2) =
            ((unsigned int)l1 << 16) | l0;
    }
}

extern "C" void kernel_launch(void* const* d_in, const int* in_sizes, int n_in,
                              void* d_out, int out_size, void* d_ws, size_t ws_size,
                              hipStream_t stream) {
    const float* x   = (const float*)d_in[0];
    const int*   ei  = (const int*)d_in[1];
    const int*   bat = (const int*)d_in[2];
    const float* W1  = (const float*)d_in[3];
    const float* b1  = (const float*)d_in[4];
    const float* W2  = (const float*)d_in[5];
    const float* b2  = (const float*)d_in[6];
    const float* W3  = (const float*)d_in[7];
    const float* b3  = (const float*)d_in[8];
    float* outp = (float*)d_out;

    const int N = in_sizes[0] / 128;   // 50000
    const int E = in_sizes[1] / 2;     // 800000
    const int* src = ei;
    const int* dst = ei + E;

    char* p = (char*)d_ws;
    auto alloc = [&](size_t bytes) -> void* {
        void* r = (void*)p;
        p += (bytes + 255) & ~(size_t)255;
        return r;
    };
    int*   cnt      = (int*)alloc((size_t)N * 4);
    int*   off      = (int*)alloc((size_t)(N + 1) * 4);
    int*   cursor   = (int*)alloc((size_t)N * 4);
    float* dinv     = (float*)alloc((size_t)N * 4);
    int*   csr_src  = (int*)alloc((size_t)E * 4);
    float* csr_norm = (float*)alloc((size_t)E * 4);
    unsigned short* Hb = (unsigned short*)alloc((size_t)N * 128 * 2);  // gemm out / agg in
    unsigned short* Ah = (unsigned short*)alloc((size_t)N * 128 * 2);  // agg out hi / x hi
    unsigned short* Al = (unsigned short*)alloc((size_t)N * 128 * 2);  // agg out lo / x lo
    unsigned short* W1h = (unsigned short*)alloc(16384 * 2);
    unsigned short* W1l = (unsigned short*)alloc(16384 * 2);
    unsigned short* W2h = (unsigned short*)alloc(16384 * 2);
    unsigned short* W2l = (unsigned short*)alloc(16384 * 2);
    unsigned short* W3h = (unsigned short*)alloc(16384 * 2);
    unsigned short* W3l = (unsigned short*)alloc(16384 * 2);

    // ---- setup: degrees, dinv, CSR, operand splits ----
    hipLaunchKernelGGL(zero_f32_kernel, dim3(cdiv_i(out_size, 256)), dim3(256), 0, stream,
                       outp, out_size);
    hipLaunchKernelGGL(zero_i32_kernel, dim3(cdiv_i(N, 256)), dim3(256), 0, stream, cnt, N);
    hipLaunchKernelGGL(count_kernel, dim3(cdiv_i(E, 256)), dim3(256), 0, stream, dst, cnt, E);
    hipLaunchKernelGGL(dinv_kernel, dim3(cdiv_i(N, 256)), dim3(256), 0, stream, cnt, dinv, N);
    hipLaunchKernelGGL(scan_kernel, dim3(1), dim3(256), 0, stream, cnt, off, N);
    hipLaunchKernelGGL(copy_i32_kernel, dim3(cdiv_i(N, 256)), dim3(256), 0, stream, off, cursor, N);
    hipLaunchKernelGGL(fill_kernel, dim3(cdiv_i(E, 256)), dim3(256), 0, stream,
                       src, dst, dinv, cursor, csr_src, csr_norm, E);
    hipLaunchKernelGGL(split_x_kernel, dim3(cdiv_i(N * 32, 256)), dim3(256), 0, stream,
                       x, Ah, Al, N * 32);
    hipLaunchKernelGGL(split_w_kernel, dim3(64), dim3(256), 0, stream, W1, W1h, W1l);
    hipLaunchKernelGGL(split_w_kernel, dim3(64), dim3(256), 0, stream, W2, W2h, W2l);
    hipLaunchKernelGGL(split_w_kernel, dim3(64), dim3(256), 0, stream, W3, W3h, W3l);

    const int gemm_grid = cdiv_i(N, 128);
    const int agg_grid  = cdiv_i(N, 4);

    // ---- layer 1 ----
    hipLaunchKernelGGL(gemm_mfma_kernel, dim3(gemm_grid), dim3(256), 0, stream,
                       Ah, Al, W1h, W1l, Hb, N);
    hipLaunchKernelGGL((agg_kernel<1, 0>), dim3(agg_grid), dim3(256), 0, stream,
                       Hb, off, csr_src, csr_norm, dinv, b1, bat, Ah, Al, outp, N);
    // ---- layer 2 ----
    hipLaunchKernelGGL(gemm_mfma_kernel, dim3(gemm_grid), dim3(256), 0, stream,
                       Ah, Al, W2h, W2l, Hb, N);
    hipLaunchKernelGGL((agg_kernel<1, 0>), dim3(agg_grid), dim3(256), 0, stream,
                       Hb, off, csr_src, csr_norm, dinv, b2, bat, Ah, Al, outp, N);
    // ---- layer 3 + fused pooling ----
    hipLaunchKernelGGL(gemm_mfma_kernel, dim3(gemm_grid), dim3(256), 0, stream,
                       Ah, Al, W3h, W3l, Hb, N);
    hipLaunchKernelGGL((agg_kernel<0, 1>), dim3(agg_grid), dim3(256), 0, stream,
                       Hb, off, csr_src, csr_norm, dinv, b3, bat, Ah, Al, outp, N);
}

// Round 10
// 552.639 us; speedup vs baseline: 1.1306x; 1.0001x over previous
//
#include <hip/hip_runtime.h>
#include <cstdint>
#include <cstddef>

// ---------------------------------------------------------------------------
// 3-layer GCN + global_add_pool.
// R7 changes vs R6 (552us; agg 3x93us latency-bound: FETCH halved but dur -7%):
//  - agg: edge-parallel wave layout (4 edges x 16 lanes x 8 cols, 16B/lane
//    gathers) -> 4x memory-level parallelism; shfl_xor reduce at end.
//  - scan: 3-phase parallel (blocksums -> 1-wave partial scan -> final),
//    removes the 49-serial-tile latency chain.
//  - gemm: wave tile 32->16 rows, grid 391->782 blocks, 2x occupancy.
// ---------------------------------------------------------------------------

typedef __attribute__((ext_vector_type(8))) short short8b;  // 8 bf16 = 4 VGPR
typedef __attribute__((ext_vector_type(4))) float f32x4;

static inline int cdiv_i(int a, int b) { return (a + b - 1) / b; }

__device__ inline unsigned short f2bf(float f) {  // RNE f32->bf16
    union { float f; unsigned int u; } v; v.f = f;
    unsigned int r = v.u + 0x7fffu + ((v.u >> 16) & 1u);
    return (unsigned short)(r >> 16);
}
__device__ inline float bf2f(unsigned short b) {
    union { unsigned int u; float f; } v; v.u = ((unsigned int)b) << 16;
    return v.f;
}

__global__ void zero_f32_kernel(float* __restrict__ p, int n) {
    int i = blockIdx.x * 256 + threadIdx.x;
    if (i < n) p[i] = 0.0f;
}
__global__ void zero_i32_kernel(int* __restrict__ p, int n) {
    int i = blockIdx.x * 256 + threadIdx.x;
    if (i < n) p[i] = 0;
}
__global__ void count_kernel(const int* __restrict__ dst, int* __restrict__ cnt, int E) {
    int i = blockIdx.x * 256 + threadIdx.x;
    if (i < E) atomicAdd(&cnt[dst[i]], 1);
}
__global__ void dinv_kernel(const int* __restrict__ cnt, float* __restrict__ dinv, int n) {
    int i = blockIdx.x * 256 + threadIdx.x;
    if (i < n) dinv[i] = rsqrtf((float)(cnt[i] + 1));
}

// ---- 3-phase scan: per-1024-chunk sums -> 1-wave exclusive scan -> final ----
__global__ __launch_bounds__(256) void scan_blocksum_kernel(const int* __restrict__ cnt,
                                                            int* __restrict__ psum, int n) {
    __shared__ int ws[4];
    int b = blockIdx.x, tid = threadIdx.x;
    int i0 = b * 1024 + tid * 4;
    int s = 0;
    if (i0 + 3 < n) {
        int4 v = *(const int4*)(cnt + i0);
        s = v.x + v.y + v.z + v.w;
    } else {
        for (int j = 0; j < 4; ++j) if (i0 + j < n) s += cnt[i0 + j];
    }
    #pragma unroll
    for (int d = 1; d < 64; d <<= 1) s += __shfl_xor(s, d, 64);
    int lane = tid & 63, wid = tid >> 6;
    if (lane == 0) ws[wid] = s;
    __syncthreads();
    if (tid == 0) psum[b] = ws[0] + ws[1] + ws[2] + ws[3];
}

// single wave scans np (<=64) partials; also writes off[n] = grand total
__global__ void scan_partials_kernel(const int* __restrict__ psum, int* __restrict__ pbase,
                                     int* __restrict__ off, int n, int np) {
    int lane = threadIdx.x;
    int v = (lane < np) ? psum[lane] : 0;
    int s = v;
    #pragma unroll
    for (int d = 1; d < 64; d <<= 1) {
        int u = __shfl_up(s, d, 64);
        if (lane >= d) s += u;
    }
    if (lane < np) pbase[lane] = s - v;
    if (lane == 63) off[n] = s;
}

__global__ __launch_bounds__(256) void scan_final_kernel(const int* __restrict__ cnt,
                                                         const int* __restrict__ pbase,
                                                         int* __restrict__ off, int n) {
    __shared__ int wsum[4];
    int b = blockIdx.x, tid = threadIdx.x;
    int lane = tid & 63, wid = tid >> 6;
    int i0 = b * 1024 + tid * 4;
    int v0 = (i0 + 0 < n) ? cnt[i0 + 0] : 0;
    int v1 = (i0 + 1 < n) ? cnt[i0 + 1] : 0;
    int v2 = (i0 + 2 < n) ? cnt[i0 + 2] : 0;
    int v3 = (i0 + 3 < n) ? cnt[i0 + 3] : 0;
    int local = v0 + v1 + v2 + v3;
    int s = local;
    #pragma unroll
    for (int d = 1; d < 64; d <<= 1) {
        int u = __shfl_up(s, d, 64);
        if (lane >= d) s += u;
    }
    if (lane == 63) wsum[wid] = s;
    __syncthreads();
    int woff = 0;
    for (int w = 0; w < wid; ++w) woff += wsum[w];
    int excl = pbase[b] + woff + (s - local);
    if (i0 + 0 < n) off[i0 + 0] = excl;
    if (i0 + 1 < n) off[i0 + 1] = excl + v0;
    if (i0 + 2 < n) off[i0 + 2] = excl + v0 + v1;
    if (i0 + 3 < n) off[i0 + 3] = excl + v0 + v1 + v2;
}

__global__ void copy_i32_kernel(const int* __restrict__ a, int* __restrict__ b, int n) {
    int i = blockIdx.x * 256 + threadIdx.x;
    if (i < n) b[i] = a[i];
}

__global__ void fill_kernel(const int* __restrict__ src, const int* __restrict__ dst,
                            const float* __restrict__ dinv, int* __restrict__ cursor,
                            int* __restrict__ csr_src, float* __restrict__ csr_norm, int E) {
    int i = blockIdx.x * 256 + threadIdx.x;
    if (i < E) {
        int s = src[i], d = dst[i];
        int pos = atomicAdd(&cursor[d], 1);
        csr_src[pos] = s;
        csr_norm[pos] = dinv[s] * dinv[d];
    }
}

// x fp32 -> xhi/xlo bf16 (4 elems/thread)
__global__ void split_x_kernel(const float* __restrict__ x,
                               unsigned short* __restrict__ xh,
                               unsigned short* __restrict__ xl, int n4) {
    int i = blockIdx.x * 256 + threadIdx.x;
    if (i >= n4) return;
    float4 v = ((const float4*)x)[i];
    unsigned short h0 = f2bf(v.x), h1 = f2bf(v.y), h2 = f2bf(v.z), h3 = f2bf(v.w);
    unsigned short l0 = f2bf(v.x - bf2f(h0)), l1 = f2bf(v.y - bf2f(h1));
    unsigned short l2 = f2bf(v.z - bf2f(h2)), l3 = f2bf(v.w - bf2f(h3));
    ushort4 hv; hv.x = h0; hv.y = h1; hv.z = h2; hv.w = h3;
    ushort4 lv; lv.x = l0; lv.y = l1; lv.z = l2; lv.w = l3;
    ((ushort4*)xh)[i] = hv;
    ((ushort4*)xl)[i] = lv;
}

// W[128][128] fp32 (row k, col n) -> hi/lo bf16 in MFMA B-fragment order:
// idx = ((kt*8+ct)*64 + lane)*8 + j  <->  k = kt*32+(lane>>4)*8+j, n = ct*16+(lane&15)
__global__ void split_w_kernel(const float* __restrict__ W,
                               unsigned short* __restrict__ Wh,
                               unsigned short* __restrict__ Wl) {
    int t = blockIdx.x * 256 + threadIdx.x;  // 0..16383
    if (t >= 16384) return;
    int j = t & 7, lane = (t >> 3) & 63, ct = (t >> 9) & 7, kt = (t >> 12) & 3;
    int k = kt * 32 + (lane >> 4) * 8 + j;
    int nn = ct * 16 + (lane & 15);
    float w = W[k * 128 + nn];
    unsigned short h = f2bf(w);
    Wh[t] = h;
    Wl[t] = f2bf(w - bf2f(h));
}

// C[n,128] = (Ahi+Alo) @ (Whi+Wlo), 3 bf16 MFMA products.
// Wave = 16 rows x 128 cols (8 ct accumulators); block = 4 waves = 64 rows.
// grid = cdiv(n,64) = 782 -> ~12 waves/CU for latency hiding.
__global__ __launch_bounds__(256) void gemm_mfma_kernel(
    const unsigned short* __restrict__ Ahi, const unsigned short* __restrict__ Alo,
    const unsigned short* __restrict__ Whf, const unsigned short* __restrict__ Wlf,
    unsigned short* __restrict__ hout, int n) {
    int wave = threadIdx.x >> 6, lane = threadIdx.x & 63;
    int r0 = blockIdx.x * 64 + wave * 16;
    int arow = r0 + (lane & 15);
    int la = min(arow, n - 1);
    int kgrp = (lane >> 4) * 8;

    f32x4 acc[8];
    #pragma unroll
    for (int c = 0; c < 8; ++c) acc[c] = (f32x4){0.f, 0.f, 0.f, 0.f};

    #pragma unroll
    for (int kt = 0; kt < 4; ++kt) {
        int koff = kt * 32 + kgrp;
        short8b a_h = *(const short8b*)(Ahi + (size_t)la * 128 + koff);
        short8b a_l = *(const short8b*)(Alo + (size_t)la * 128 + koff);
        const unsigned short* wb = Whf + ((size_t)(kt * 8) * 64 + lane) * 8;
        const unsigned short* lb = Wlf + ((size_t)(kt * 8) * 64 + lane) * 8;
        #pragma unroll
        for (int ct = 0; ct < 8; ++ct) {
            short8b wh = *(const short8b*)(wb + (size_t)ct * 512);
            short8b wl = *(const short8b*)(lb + (size_t)ct * 512);
            acc[ct] = __builtin_amdgcn_mfma_f32_16x16x32_bf16(a_h, wh, acc[ct], 0, 0, 0);
            acc[ct] = __builtin_amdgcn_mfma_f32_16x16x32_bf16(a_l, wh, acc[ct], 0, 0, 0);
            acc[ct] = __builtin_amdgcn_mfma_f32_16x16x32_bf16(a_h, wl, acc[ct], 0, 0, 0);
        }
    }
    // D layout: row = (lane>>4)*4 + reg, col = lane&15  [verified on HW in R6]
    int rb = r0 + (lane >> 4) * 4;
    int col = lane & 15;
    #pragma unroll
    for (int ct = 0; ct < 8; ++ct)
        #pragma unroll
        for (int i = 0; i < 4; ++i) {
            int rr = rb + i;
            if (rr < n) hout[(size_t)rr * 128 + ct * 16 + col] = f2bf(acc[ct][i]);
        }
}

// Edge-parallel aggregation: wave = 1 node; lane = (ep, cg), ep=lane>>4 is a
// 4-way edge-parallel index, cg=lane&15 covers bf16 cols [cg*8, cg*8+8).
// Each lane gathers 16B/edge; 4 edges in flight -> 4x MLP vs R6.
template <int RELU, int POOL>
__global__ __launch_bounds__(256) void agg_kernel(
    const unsigned short* __restrict__ h, const int* __restrict__ off,
    const int* __restrict__ csr_src, const float* __restrict__ csr_norm,
    const float* __restrict__ dinv, const float* __restrict__ bias,
    const int* __restrict__ batch,
    unsigned short* __restrict__ ah, unsigned short* __restrict__ al,
    float* __restrict__ pool_out, int n) {
    int node = blockIdx.x * 4 + (threadIdx.x >> 6);
    if (node >= n) return;
    int lane = threadIdx.x & 63;
    int ep = lane >> 4;
    int cg = lane & 15;
    int c0 = cg * 8;

    float acc[8];
    #pragma unroll
    for (int j = 0; j < 8; ++j) acc[j] = 0.f;

    if (ep == 0) {  // self-loop term
        float di = dinv[node];
        float w = di * di;
        short8b v = *(const short8b*)(h + (size_t)node * 128 + c0);
        #pragma unroll
        for (int j = 0; j < 8; ++j) acc[j] = w * bf2f((unsigned short)v[j]);
    }
    int e0 = off[node], e1 = off[node + 1];
    for (int e = e0 + ep; e < e1; e += 4) {
        int s = csr_src[e];
        float w = csr_norm[e];
        short8b v = *(const short8b*)(h + (size_t)s * 128 + c0);
        #pragma unroll
        for (int j = 0; j < 8; ++j) acc[j] = fmaf(w, bf2f((unsigned short)v[j]), acc[j]);
    }
    // reduce across the 4 ep groups (lane bits 4,5)
    #pragma unroll
    for (int j = 0; j < 8; ++j) {
        acc[j] += __shfl_xor(acc[j], 16, 64);
        acc[j] += __shfl_xor(acc[j], 32, 64);
    }
    if (ep == 0) {
        float r[8];
        #pragma unroll
        for (int j = 0; j < 8; ++j) {
            r[j] = acc[j] + bias[c0 + j];
            if (RELU) r[j] = fmaxf(r[j], 0.f);
        }
        if (POOL) {
            int g = batch[node];
            #pragma unroll
            for (int j = 0; j < 8; ++j)
                atomicAdd(pool_out + (size_t)g * 128 + c0 + j, r[j]);
        } else {
            short8b hv, lv;
            #pragma unroll
            for (int j = 0; j < 8; ++j) {
                unsigned short hb = f2bf(r[j]);
                hv[j] = (short)hb;
                lv[j] = (short)f2bf(r[j] - bf2f(hb));
            }
            *(short8b*)(ah + (size_t)node * 128 + c0) = hv;
            *(short8b*)(al + (size_t)node * 128 + c0) = lv;
        }
    }
}

extern "C" void kernel_launch(void* const* d_in, const int* in_sizes, int n_in,
                              void* d_out, int out_size, void* d_ws, size_t ws_size,
                              hipStream_t stream) {
    const float* x   = (const float*)d_in[0];
    const int*   ei  = (const int*)d_in[1];
    const int*   bat = (const int*)d_in[2];
    const float* W1  = (const float*)d_in[3];
    const float* b1  = (const float*)d_in[4];
    const float* W2  = (const float*)d_in[5];
    const float* b2  = (const float*)d_in[6];
    const float* W3  = (const float*)d_in[7];
    const float* b3  = (const float*)d_in[8];
    float* outp = (float*)d_out;

    const int N = in_sizes[0] / 128;   // 50000
    const int E = in_sizes[1] / 2;     // 800000
    const int* src = ei;
    const int* dst = ei + E;
    const int NP = cdiv_i(N, 1024);    // scan partial count (49)

    char* p = (char*)d_ws;
    auto alloc = [&](size_t bytes) -> void* {
        void* r = (void*)p;
        p += (bytes + 255) & ~(size_t)255;
        return r;
    };
    int*   cnt      = (int*)alloc((size_t)N * 4);
    int*   off      = (int*)alloc((size_t)(N + 1) * 4);
    int*   cursor   = (int*)alloc((size_t)N * 4);
    float* dinv     = (float*)alloc((size_t)N * 4);
    int*   psum     = (int*)alloc((size_t)(NP + 1) * 4);
    int*   pbase    = (int*)alloc((size_t)(NP + 1) * 4);
    int*   csr_src  = (int*)alloc((size_t)E * 4);
    float* csr_norm = (float*)alloc((size_t)E * 4);
    unsigned short* Hb = (unsigned short*)alloc((size_t)N * 128 * 2);  // gemm out / agg in
    unsigned short* Ah = (unsigned short*)alloc((size_t)N * 128 * 2);  // agg out hi / x hi
    unsigned short* Al = (unsigned short*)alloc((size_t)N * 128 * 2);  // agg out lo / x lo
    unsigned short* W1h = (unsigned short*)alloc(16384 * 2);
    unsigned short* W1l = (unsigned short*)alloc(16384 * 2);
    unsigned short* W2h = (unsigned short*)alloc(16384 * 2);
    unsigned short* W2l = (unsigned short*)alloc(16384 * 2);
    unsigned short* W3h = (unsigned short*)alloc(16384 * 2);
    unsigned short* W3l = (unsigned short*)alloc(16384 * 2);

    // ---- setup: degrees, dinv, CSR, operand splits ----
    hipLaunchKernelGGL(zero_f32_kernel, dim3(cdiv_i(out_size, 256)), dim3(256), 0, stream,
                       outp, out_size);
    hipLaunchKernelGGL(zero_i32_kernel, dim3(cdiv_i(N, 256)), dim3(256), 0, stream, cnt, N);
    hipLaunchKernelGGL(count_kernel, dim3(cdiv_i(E, 256)), dim3(256), 0, stream, dst, cnt, E);
    hipLaunchKernelGGL(dinv_kernel, dim3(cdiv_i(N, 256)), dim3(256), 0, stream, cnt, dinv, N);
    hipLaunchKernelGGL(scan_blocksum_kernel, dim3(NP), dim3(256), 0, stream, cnt, psum, N);
    hipLaunchKernelGGL(scan_partials_kernel, dim3(1), dim3(64), 0, stream,
                       psum, pbase, off, N, NP);
    hipLaunchKernelGGL(scan_final_kernel, dim3(NP), dim3(256), 0, stream, cnt, pbase, off, N);
    hipLaunchKernelGGL(copy_i32_kernel, dim3(cdiv_i(N, 256)), dim3(256), 0, stream, off, cursor, N);
    hipLaunchKernelGGL(fill_kernel, dim3(cdiv_i(E, 256)), dim3(256), 0, stream,
                       src, dst, dinv, cursor, csr_src, csr_norm, E);
    hipLaunchKernelGGL(split_x_kernel, dim3(cdiv_i(N * 32, 256)), dim3(256), 0, stream,
                       x, Ah, Al, N * 32);
    hipLaunchKernelGGL(split_w_kernel, dim3(64), dim3(256), 0, stream, W1, W1h, W1l);
    hipLaunchKernelGGL(split_w_kernel, dim3(64), dim3(256), 0, stream, W2, W2h, W2l);
    hipLaunchKernelGGL(split_w_kernel, dim3(64), dim3(256), 0, stream, W3, W3h, W3l);

    const int gemm_grid = cdiv_i(N, 64);
    const int agg_grid  = cdiv_i(N, 4);

    // ---- layer 1 ----
    hipLaunchKernelGGL(gemm_mfma_kernel, dim3(gemm_grid), dim3(256), 0, stream,
                       Ah, Al, W1h, W1l, Hb, N);
    hipLaunchKernelGGL((agg_kernel<1, 0>), dim3(agg_grid), dim3(256), 0, stream,
                       Hb, off, csr_src, csr_norm, dinv, b1, bat, Ah, Al, outp, N);
    // ---- layer 2 ----
    hipLaunchKernelGGL(gemm_mfma_kernel, dim3(gemm_grid), dim3(256), 0, stream,
                       Ah, Al, W2h, W2l, Hb, N);
    hipLaunchKernelGGL((agg_kernel<1, 0>), dim3(agg_grid), dim3(256), 0, stream,
                       Hb, off, csr_src, csr_norm, dinv, b2, bat, Ah, Al, outp, N);
    // ---- layer 3 + fused pooling ----
    hipLaunchKernelGGL(gemm_mfma_kernel, dim3(gemm_grid), dim3(256), 0, stream,
                       Ah, Al, W3h, W3l, Hb, N);
    hipLaunchKernelGGL((agg_kernel<0, 1>), dim3(agg_grid), dim3(256), 0, stream,
                       Hb, off, csr_src, csr_norm, dinv, b3, bat, Ah, Al, outp, N);
}

// Round 11
// 365.618 us; speedup vs baseline: 1.7089x; 1.5115x over previous
//
#include <hip/hip_runtime.h>
#include <cstdint>
#include <cstddef>

// ---------------------------------------------------------------------------
// 3-layer GCN + global_add_pool.
// R11 change vs R10 (552us; POOL agg = 240us, WRITE 200MB from 6.4M atomics
// into 256KB -> contention-serialized):
//  - layer-3 agg writes per-node fp32 rows (MODE=1, no atomics).
//  - new pool_kernel: block per graph (batch is SORTED), binary-search range,
//    4-wave strided fp32 accumulate, LDS reduce, coalesced 512B store.
//  - zero_f32(out) dropped (pool writes every output element).
// Unchanged: edge-parallel agg, hi/lo-split MFMA gemm, 3-phase scan.
// ---------------------------------------------------------------------------

typedef __attribute__((ext_vector_type(8))) short short8b;  // 8 bf16 = 4 VGPR
typedef __attribute__((ext_vector_type(4))) float f32x4;

static inline int cdiv_i(int a, int b) { return (a + b - 1) / b; }

__device__ inline unsigned short f2bf(float f) {  // RNE f32->bf16
    union { float f; unsigned int u; } v; v.f = f;
    unsigned int r = v.u + 0x7fffu + ((v.u >> 16) & 1u);
    return (unsigned short)(r >> 16);
}
__device__ inline float bf2f(unsigned short b) {
    union { unsigned int u; float f; } v; v.u = ((unsigned int)b) << 16;
    return v.f;
}

__global__ void zero_i32_kernel(int* __restrict__ p, int n) {
    int i = blockIdx.x * 256 + threadIdx.x;
    if (i < n) p[i] = 0;
}
__global__ void count_kernel(const int* __restrict__ dst, int* __restrict__ cnt, int E) {
    int i = blockIdx.x * 256 + threadIdx.x;
    if (i < E) atomicAdd(&cnt[dst[i]], 1);
}
__global__ void dinv_kernel(const int* __restrict__ cnt, float* __restrict__ dinv, int n) {
    int i = blockIdx.x * 256 + threadIdx.x;
    if (i < n) dinv[i] = rsqrtf((float)(cnt[i] + 1));
}

// ---- 3-phase scan: per-1024-chunk sums -> 1-wave exclusive scan -> final ----
__global__ __launch_bounds__(256) void scan_blocksum_kernel(const int* __restrict__ cnt,
                                                            int* __restrict__ psum, int n) {
    __shared__ int ws[4];
    int b = blockIdx.x, tid = threadIdx.x;
    int i0 = b * 1024 + tid * 4;
    int s = 0;
    if (i0 + 3 < n) {
        int4 v = *(const int4*)(cnt + i0);
        s = v.x + v.y + v.z + v.w;
    } else {
        for (int j = 0; j < 4; ++j) if (i0 + j < n) s += cnt[i0 + j];
    }
    #pragma unroll
    for (int d = 1; d < 64; d <<= 1) s += __shfl_xor(s, d, 64);
    int lane = tid & 63, wid = tid >> 6;
    if (lane == 0) ws[wid] = s;
    __syncthreads();
    if (tid == 0) psum[b] = ws[0] + ws[1] + ws[2] + ws[3];
}

__global__ void scan_partials_kernel(const int* __restrict__ psum, int* __restrict__ pbase,
                                     int* __restrict__ off, int n, int np) {
    int lane = threadIdx.x;
    int v = (lane < np) ? psum[lane] : 0;
    int s = v;
    #pragma unroll
    for (int d = 1; d < 64; d <<= 1) {
        int u = __shfl_up(s, d, 64);
        if (lane >= d) s += u;
    }
    if (lane < np) pbase[lane] = s - v;
    if (lane == 63) off[n] = s;
}

__global__ __launch_bounds__(256) void scan_final_kernel(const int* __restrict__ cnt,
                                                         const int* __restrict__ pbase,
                                                         int* __restrict__ off, int n) {
    __shared__ int wsum[4];
    int b = blockIdx.x, tid = threadIdx.x;
    int lane = tid & 63, wid = tid >> 6;
    int i0 = b * 1024 + tid * 4;
    int v0 = (i0 + 0 < n) ? cnt[i0 + 0] : 0;
    int v1 = (i0 + 1 < n) ? cnt[i0 + 1] : 0;
    int v2 = (i0 + 2 < n) ? cnt[i0 + 2] : 0;
    int v3 = (i0 + 3 < n) ? cnt[i0 + 3] : 0;
    int local = v0 + v1 + v2 + v3;
    int s = local;
    #pragma unroll
    for (int d = 1; d < 64; d <<= 1) {
        int u = __shfl_up(s, d, 64);
        if (lane >= d) s += u;
    }
    if (lane == 63) wsum[wid] = s;
    __syncthreads();
    int woff = 0;
    for (int w = 0; w < wid; ++w) woff += wsum[w];
    int excl = pbase[b] + woff + (s - local);
    if (i0 + 0 < n) off[i0 + 0] = excl;
    if (i0 + 1 < n) off[i0 + 1] = excl + v0;
    if (i0 + 2 < n) off[i0 + 2] = excl + v0 + v1;
    if (i0 + 3 < n) off[i0 + 3] = excl + v0 + v1 + v2;
}

__global__ void copy_i32_kernel(const int* __restrict__ a, int* __restrict__ b, int n) {
    int i = blockIdx.x * 256 + threadIdx.x;
    if (i < n) b[i] = a[i];
}

__global__ void fill_kernel(const int* __restrict__ src, const int* __restrict__ dst,
                            const float* __restrict__ dinv, int* __restrict__ cursor,
                            int* __restrict__ csr_src, float* __restrict__ csr_norm, int E) {
    int i = blockIdx.x * 256 + threadIdx.x;
    if (i < E) {
        int s = src[i], d = dst[i];
        int pos = atomicAdd(&cursor[d], 1);
        csr_src[pos] = s;
        csr_norm[pos] = dinv[s] * dinv[d];
    }
}

// x fp32 -> xhi/xlo bf16 (4 elems/thread)
__global__ void split_x_kernel(const float* __restrict__ x,
                               unsigned short* __restrict__ xh,
                               unsigned short* __restrict__ xl, int n4) {
    int i = blockIdx.x * 256 + threadIdx.x;
    if (i >= n4) return;
    float4 v = ((const float4*)x)[i];
    unsigned short h0 = f2bf(v.x), h1 = f2bf(v.y), h2 = f2bf(v.z), h3 = f2bf(v.w);
    unsigned short l0 = f2bf(v.x - bf2f(h0)), l1 = f2bf(v.y - bf2f(h1));
    unsigned short l2 = f2bf(v.z - bf2f(h2)), l3 = f2bf(v.w - bf2f(h3));
    ushort4 hv; hv.x = h0; hv.y = h1; hv.z = h2; hv.w = h3;
    ushort4 lv; lv.x = l0; lv.y = l1; lv.z = l2; lv.w = l3;
    ((ushort4*)xh)[i] = hv;
    ((ushort4*)xl)[i] = lv;
}

// W[128][128] fp32 (row k, col n) -> hi/lo bf16 in MFMA B-fragment order:
// idx = ((kt*8+ct)*64 + lane)*8 + j  <->  k = kt*32+(lane>>4)*8+j, n = ct*16+(lane&15)
__global__ void split_w_kernel(const float* __restrict__ W,
                               unsigned short* __restrict__ Wh,
                               unsigned short* __restrict__ Wl) {
    int t = blockIdx.x * 256 + threadIdx.x;  // 0..16383
    if (t >= 16384) return;
    int j = t & 7, lane = (t >> 3) & 63, ct = (t >> 9) & 7, kt = (t >> 12) & 3;
    int k = kt * 32 + (lane >> 4) * 8 + j;
    int nn = ct * 16 + (lane & 15);
    float w = W[k * 128 + nn];
    unsigned short h = f2bf(w);
    Wh[t] = h;
    Wl[t] = f2bf(w - bf2f(h));
}

// C[n,128] = (Ahi+Alo) @ (Whi+Wlo), 3 bf16 MFMA products.
// Wave = 16 rows x 128 cols; block = 4 waves = 64 rows; grid = cdiv(n,64).
__global__ __launch_bounds__(256) void gemm_mfma_kernel(
    const unsigned short* __restrict__ Ahi, const unsigned short* __restrict__ Alo,
    const unsigned short* __restrict__ Whf, const unsigned short* __restrict__ Wlf,
    unsigned short* __restrict__ hout, int n) {
    int wave = threadIdx.x >> 6, lane = threadIdx.x & 63;
    int r0 = blockIdx.x * 64 + wave * 16;
    int arow = r0 + (lane & 15);
    int la = min(arow, n - 1);
    int kgrp = (lane >> 4) * 8;

    f32x4 acc[8];
    #pragma unroll
    for (int c = 0; c < 8; ++c) acc[c] = (f32x4){0.f, 0.f, 0.f, 0.f};

    #pragma unroll
    for (int kt = 0; kt < 4; ++kt) {
        int koff = kt * 32 + kgrp;
        short8b a_h = *(const short8b*)(Ahi + (size_t)la * 128 + koff);
        short8b a_l = *(const short8b*)(Alo + (size_t)la * 128 + koff);
        const unsigned short* wb = Whf + ((size_t)(kt * 8) * 64 + lane) * 8;
        const unsigned short* lb = Wlf + ((size_t)(kt * 8) * 64 + lane) * 8;
        #pragma unroll
        for (int ct = 0; ct < 8; ++ct) {
            short8b wh = *(const short8b*)(wb + (size_t)ct * 512);
            short8b wl = *(const short8b*)(lb + (size_t)ct * 512);
            acc[ct] = __builtin_amdgcn_mfma_f32_16x16x32_bf16(a_h, wh, acc[ct], 0, 0, 0);
            acc[ct] = __builtin_amdgcn_mfma_f32_16x16x32_bf16(a_l, wh, acc[ct], 0, 0, 0);
            acc[ct] = __builtin_amdgcn_mfma_f32_16x16x32_bf16(a_h, wl, acc[ct], 0, 0, 0);
        }
    }
    // D layout: row = (lane>>4)*4 + reg, col = lane&15  [verified on HW in R6]
    int rb = r0 + (lane >> 4) * 4;
    int col = lane & 15;
    #pragma unroll
    for (int ct = 0; ct < 8; ++ct)
        #pragma unroll
        for (int i = 0; i < 4; ++i) {
            int rr = rb + i;
            if (rr < n) hout[(size_t)rr * 128 + ct * 16 + col] = f2bf(acc[ct][i]);
        }
}

// Edge-parallel aggregation: wave = 1 node; lane = (ep, cg); ep=lane>>4 gives
// 4 edges in flight; cg=lane&15 covers bf16 cols [cg*8, cg*8+8), 16B gathers.
// MODE 0: write bf16 hi/lo pair (next GEMM's A). MODE 1: write fp32 row.
template <int RELU, int MODE>
__global__ __launch_bounds__(256) void agg_kernel(
    const unsigned short* __restrict__ h, const int* __restrict__ off,
    const int* __restrict__ csr_src, const float* __restrict__ csr_norm,
    const float* __restrict__ dinv, const float* __restrict__ bias,
    unsigned short* __restrict__ ah, unsigned short* __restrict__ al,
    float* __restrict__ cf32, int n) {
    int node = blockIdx.x * 4 + (threadIdx.x >> 6);
    if (node >= n) return;
    int lane = threadIdx.x & 63;
    int ep = lane >> 4;
    int cg = lane & 15;
    int c0 = cg * 8;

    float acc[8];
    #pragma unroll
    for (int j = 0; j < 8; ++j) acc[j] = 0.f;

    if (ep == 0) {  // self-loop term
        float di = dinv[node];
        float w = di * di;
        short8b v = *(const short8b*)(h + (size_t)node * 128 + c0);
        #pragma unroll
        for (int j = 0; j < 8; ++j) acc[j] = w * bf2f((unsigned short)v[j]);
    }
    int e0 = off[node], e1 = off[node + 1];
    for (int e = e0 + ep; e < e1; e += 4) {
        int s = csr_src[e];
        float w = csr_norm[e];
        short8b v = *(const short8b*)(h + (size_t)s * 128 + c0);
        #pragma unroll
        for (int j = 0; j < 8; ++j) acc[j] = fmaf(w, bf2f((unsigned short)v[j]), acc[j]);
    }
    // reduce across the 4 ep groups (lane bits 4,5)
    #pragma unroll
    for (int j = 0; j < 8; ++j) {
        acc[j] += __shfl_xor(acc[j], 16, 64);
        acc[j] += __shfl_xor(acc[j], 32, 64);
    }
    if (ep == 0) {
        float r[8];
        #pragma unroll
        for (int j = 0; j < 8; ++j) {
            r[j] = acc[j] + bias[c0 + j];
            if (RELU) r[j] = fmaxf(r[j], 0.f);
        }
        if (MODE == 1) {  // fp32 row for pooling pass
            float4 lo = make_float4(r[0], r[1], r[2], r[3]);
            float4 hi = make_float4(r[4], r[5], r[6], r[7]);
            *(float4*)(cf32 + (size_t)node * 128 + c0) = lo;
            *(float4*)(cf32 + (size_t)node * 128 + c0 + 4) = hi;
        } else {
            short8b hv, lv;
            #pragma unroll
            for (int j = 0; j < 8; ++j) {
                unsigned short hb = f2bf(r[j]);
                hv[j] = (short)hb;
                lv[j] = (short)f2bf(r[j] - bf2f(hb));
            }
            *(short8b*)(ah + (size_t)node * 128 + c0) = hv;
            *(short8b*)(al + (size_t)node * 128 + c0) = lv;
        }
    }
}

// global_add_pool over SORTED batch ids: one block per graph.
// Binary-search [lo,hi) in batch; 4 waves stride nodes; LDS reduce; one
// coalesced 512B store. Covers every graph (empty graph -> zeros).
__global__ __launch_bounds__(256) void pool_kernel(const float* __restrict__ hsrc,
                                                   const int* __restrict__ batch,
                                                   float* __restrict__ out, int n) {
    __shared__ int s_lo, s_hi;
    __shared__ float red[4][128];
    int g = blockIdx.x;
    if (threadIdx.x == 0) {
        int lo = 0, hi = n;
        while (lo < hi) { int m = (lo + hi) >> 1; if (batch[m] < g) lo = m + 1; else hi = m; }
        s_lo = lo;
        lo = 0; hi = n;
        while (lo < hi) { int m = (lo + hi) >> 1; if (batch[m] < g + 1) lo = m + 1; else hi = m; }
        s_hi = lo;
    }
    __syncthreads();
    int lo = s_lo, hi = s_hi;
    int wave = threadIdx.x >> 6, lane = threadIdx.x & 63;
    int c2 = lane * 2;
    float ax = 0.f, ay = 0.f;
    for (int i = lo + wave; i < hi; i += 4) {
        float2 v = *(const float2*)(hsrc + (size_t)i * 128 + c2);
        ax += v.x; ay += v.y;
    }
    red[wave][c2] = ax;
    red[wave][c2 + 1] = ay;
    __syncthreads();
    if (wave == 0) {
        float a = red[0][c2] + red[1][c2] + red[2][c2] + red[3][c2];
        float b = red[0][c2 + 1] + red[1][c2 + 1] + red[2][c2 + 1] + red[3][c2 + 1];
        *(float2*)(out + (size_t)g * 128 + c2) = make_float2(a, b);
    }
}

extern "C" void kernel_launch(void* const* d_in, const int* in_sizes, int n_in,
                              void* d_out, int out_size, void* d_ws, size_t ws_size,
                              hipStream_t stream) {
    const float* x   = (const float*)d_in[0];
    const int*   ei  = (const int*)d_in[1];
    const int*   bat = (const int*)d_in[2];
    const float* W1  = (const float*)d_in[3];
    const float* b1  = (const float*)d_in[4];
    const float* W2  = (const float*)d_in[5];
    const float* b2  = (const float*)d_in[6];
    const float* W3  = (const float*)d_in[7];
    const float* b3  = (const float*)d_in[8];
    float* outp = (float*)d_out;

    const int N = in_sizes[0] / 128;   // 50000
    const int E = in_sizes[1] / 2;     // 800000
    const int NG = out_size / 128;     // 512 graphs
    const int* src = ei;
    const int* dst = ei + E;
    const int NP = cdiv_i(N, 1024);    // scan partial count (49)

    char* p = (char*)d_ws;
    auto alloc = [&](size_t bytes) -> void* {
        void* r = (void*)p;
        p += (bytes + 255) & ~(size_t)255;
        return r;
    };
    int*   cnt      = (int*)alloc((size_t)N * 4);
    int*   off      = (int*)alloc((size_t)(N + 1) * 4);
    int*   cursor   = (int*)alloc((size_t)N * 4);
    float* dinv     = (float*)alloc((size_t)N * 4);
    int*   psum     = (int*)alloc((size_t)(NP + 1) * 4);
    int*   pbase    = (int*)alloc((size_t)(NP + 1) * 4);
    int*   csr_src  = (int*)alloc((size_t)E * 4);
    float* csr_norm = (float*)alloc((size_t)E * 4);
    unsigned short* Hb = (unsigned short*)alloc((size_t)N * 128 * 2);  // gemm out / agg in
    unsigned short* Ah = (unsigned short*)alloc((size_t)N * 128 * 2);  // agg out hi / x hi
    unsigned short* Al = (unsigned short*)alloc((size_t)N * 128 * 2);  // agg out lo / x lo
    float* Cf = (float*)alloc((size_t)N * 128 * 4);                    // layer-3 fp32 rows
    unsigned short* W1h = (unsigned short*)alloc(16384 * 2);
    unsigned short* W1l = (unsigned short*)alloc(16384 * 2);
    unsigned short* W2h = (unsigned short*)alloc(16384 * 2);
    unsigned short* W2l = (unsigned short*)alloc(16384 * 2);
    unsigned short* W3h = (unsigned short*)alloc(16384 * 2);
    unsigned short* W3l = (unsigned short*)alloc(16384 * 2);

    // ---- setup: degrees, dinv, CSR, operand splits ----
    hipLaunchKernelGGL(zero_i32_kernel, dim3(cdiv_i(N, 256)), dim3(256), 0, stream, cnt, N);
    hipLaunchKernelGGL(count_kernel, dim3(cdiv_i(E, 256)), dim3(256), 0, stream, dst, cnt, E);
    hipLaunchKernelGGL(dinv_kernel, dim3(cdiv_i(N, 256)), dim3(256), 0, stream, cnt, dinv, N);
    hipLaunchKernelGGL(scan_blocksum_kernel, dim3(NP), dim3(256), 0, stream, cnt, psum, N);
    hipLaunchKernelGGL(scan_partials_kernel, dim3(1), dim3(64), 0, stream,
                       psum, pbase, off, N, NP);
    hipLaunchKernelGGL(scan_final_kernel, dim3(NP), dim3(256), 0, stream, cnt, pbase, off, N);
    hipLaunchKernelGGL(copy_i32_kernel, dim3(cdiv_i(N, 256)), dim3(256), 0, stream, off, cursor, N);
    hipLaunchKernelGGL(fill_kernel, dim3(cdiv_i(E, 256)), dim3(256), 0, stream,
                       src, dst, dinv, cursor, csr_src, csr_norm, E);
    hipLaunchKernelGGL(split_x_kernel, dim3(cdiv_i(N * 32, 256)), dim3(256), 0, stream,
                       x, Ah, Al, N * 32);
    hipLaunchKernelGGL(split_w_kernel, dim3(64), dim3(256), 0, stream, W1, W1h, W1l);
    hipLaunchKernelGGL(split_w_kernel, dim3(64), dim3(256), 0, stream, W2, W2h, W2l);
    hipLaunchKernelGGL(split_w_kernel, dim3(64), dim3(256), 0, stream, W3, W3h, W3l);

    const int gemm_grid = cdiv_i(N, 64);
    const int agg_grid  = cdiv_i(N, 4);

    // ---- layer 1 ----
    hipLaunchKernelGGL(gemm_mfma_kernel, dim3(gemm_grid), dim3(256), 0, stream,
                       Ah, Al, W1h, W1l, Hb, N);
    hipLaunchKernelGGL((agg_kernel<1, 0>), dim3(agg_grid), dim3(256), 0, stream,
                       Hb, off, csr_src, csr_norm, dinv, b1, Ah, Al, Cf, N);
    // ---- layer 2 ----
    hipLaunchKernelGGL(gemm_mfma_kernel, dim3(gemm_grid), dim3(256), 0, stream,
                       Ah, Al, W2h, W2l, Hb, N);
    hipLaunchKernelGGL((agg_kernel<1, 0>), dim3(agg_grid), dim3(256), 0, stream,
                       Hb, off, csr_src, csr_norm, dinv, b2, Ah, Al, Cf, N);
    // ---- layer 3: fp32 rows, then atomic-free pooling ----
    hipLaunchKernelGGL(gemm_mfma_kernel, dim3(gemm_grid), dim3(256), 0, stream,
                       Ah, Al, W3h, W3l, Hb, N);
    hipLaunchKernelGGL((agg_kernel<0, 1>), dim3(agg_grid), dim3(256), 0, stream,
                       Hb, off, csr_src, csr_norm, dinv, b3, Ah, Al, Cf, N);
    hipLaunchKernelGGL(pool_kernel, dim3(NG), dim3(256), 0, stream, Cf, bat, outp, N);
}